// Round 1
// baseline (1263.759 us; speedup 1.0000x reference)
//
#include <hip/hip_runtime.h>

#define NBATCH 16
#define NPTS   2048
#define MQ     2025   // grid points per batch
#define CWDIM  512

// ---------- float <-> order-preserving uint key (for atomicMax on floats) ----------
__device__ __forceinline__ unsigned fkey(float f) {
  unsigned u = __float_as_uint(f);
  return (u & 0x80000000u) ? ~u : (u | 0x80000000u);
}
__device__ __forceinline__ float funkey(unsigned u) {
  unsigned v = (u & 0x80000000u) ? (u ^ 0x80000000u) : ~u;
  return __uint_as_float(v);
}
__device__ __forceinline__ void fma4(float4& a, float s, float4 w) {
  a.x += s * w.x; a.y += s * w.y; a.z += s * w.z; a.w += s * w.w;
}

// =====================================================================
// Encoder: per block = one batch x 64 points. 4->64->128->512, max over pts,
// atomicMax(uint-encoded) into keys[B*512].
// =====================================================================
__global__ __launch_bounds__(256) void enc_kernel(
    const float* __restrict__ pts,
    const float* __restrict__ w1, const float* __restrict__ b1,
    const float* __restrict__ w2, const float* __restrict__ b2,
    const float* __restrict__ w3, const float* __restrict__ b3,
    unsigned* __restrict__ keys)
{
  __shared__ float s_pts[64][4];
  __shared__ float s_w1[4][64];
  __shared__ float s_b1[64];
  __shared__ float s_b2[128];
  __shared__ float s_h1[64][64];
  __shared__ float s_h2[64][128];
  __shared__ float s_red[8][128];

  const int t  = threadIdx.x;
  const int b  = blockIdx.x >> 5;          // 32 chunks per batch
  const int p0 = (blockIdx.x & 31) << 6;   // 64 points per chunk

  if (t < 64)
    *(float4*)&s_pts[t][0] = *(const float4*)(pts + ((size_t)b * NPTS + p0 + t) * 4);
  s_w1[t >> 6][t & 63] = w1[t];            // 4x64 = 256
  if (t < 64)  s_b1[t] = b1[t];
  if (t < 128) s_b2[t] = b2[t];
  __syncthreads();

  // layer 1: 64 pts x 64 cols (K=4)
  #pragma unroll
  for (int i = 0; i < 16; ++i) {
    int o = i * 256 + t;
    int p = o >> 6, c = o & 63;
    float acc = s_b1[c];
    #pragma unroll
    for (int k = 0; k < 4; ++k) acc += s_pts[p][k] * s_w1[k][c];
    s_h1[p][c] = fmaxf(acc, 0.f);
  }
  __syncthreads();

  const int ty = t >> 5, tx = t & 31;

  // layer 2: 64 pts x 128 cols (K=64), thread = 8 pts x 4 cols
  {
    const int c0 = tx << 2;
    float4 acc[8];
    #pragma unroll
    for (int i = 0; i < 8; ++i) acc[i] = make_float4(0.f, 0.f, 0.f, 0.f);
    for (int k = 0; k < 64; k += 4) {
      float4 q0 = *(const float4*)(w2 + (size_t)(k + 0) * 128 + c0);
      float4 q1 = *(const float4*)(w2 + (size_t)(k + 1) * 128 + c0);
      float4 q2 = *(const float4*)(w2 + (size_t)(k + 2) * 128 + c0);
      float4 q3 = *(const float4*)(w2 + (size_t)(k + 3) * 128 + c0);
      #pragma unroll
      for (int i = 0; i < 8; ++i) {
        float4 h = *(const float4*)&s_h1[ty * 8 + i][k];
        fma4(acc[i], h.x, q0); fma4(acc[i], h.y, q1);
        fma4(acc[i], h.z, q2); fma4(acc[i], h.w, q3);
      }
    }
    float4 bias = *(const float4*)&s_b2[c0];
    #pragma unroll
    for (int i = 0; i < 8; ++i) {
      float4 v;
      v.x = fmaxf(acc[i].x + bias.x, 0.f);
      v.y = fmaxf(acc[i].y + bias.y, 0.f);
      v.z = fmaxf(acc[i].z + bias.z, 0.f);
      v.w = fmaxf(acc[i].w + bias.w, 0.f);
      *(float4*)&s_h2[ty * 8 + i][c0] = v;
    }
  }
  __syncthreads();

  // layer 3 (K=128, no relu) + max over 64 pts, 4 col-chunks of 128
  for (int cc = 0; cc < 4; ++cc) {
    const int gc0 = cc * 128 + (tx << 2);
    float4 acc[8];
    #pragma unroll
    for (int i = 0; i < 8; ++i) acc[i] = make_float4(0.f, 0.f, 0.f, 0.f);
    for (int k = 0; k < 128; k += 4) {
      float4 q0 = *(const float4*)(w3 + (size_t)(k + 0) * 512 + gc0);
      float4 q1 = *(const float4*)(w3 + (size_t)(k + 1) * 512 + gc0);
      float4 q2 = *(const float4*)(w3 + (size_t)(k + 2) * 512 + gc0);
      float4 q3 = *(const float4*)(w3 + (size_t)(k + 3) * 512 + gc0);
      #pragma unroll
      for (int i = 0; i < 8; ++i) {
        float4 h = *(const float4*)&s_h2[ty * 8 + i][k];
        fma4(acc[i], h.x, q0); fma4(acc[i], h.y, q1);
        fma4(acc[i], h.z, q2); fma4(acc[i], h.w, q3);
      }
    }
    float4 bias = *(const float4*)(b3 + gc0);
    float4 mx = acc[0];
    #pragma unroll
    for (int i = 1; i < 8; ++i) {
      mx.x = fmaxf(mx.x, acc[i].x); mx.y = fmaxf(mx.y, acc[i].y);
      mx.z = fmaxf(mx.z, acc[i].z); mx.w = fmaxf(mx.w, acc[i].w);
    }
    mx.x += bias.x; mx.y += bias.y; mx.z += bias.z; mx.w += bias.w;
    *(float4*)&s_red[ty][tx << 2] = mx;
    __syncthreads();
    if (t < 128) {
      float mm = s_red[0][t];
      #pragma unroll
      for (int g = 1; g < 8; ++g) mm = fmaxf(mm, s_red[g][t]);
      atomicMax(&keys[b * CWDIM + cc * 128 + t], fkey(mm));
    }
    __syncthreads();
  }
}

// =====================================================================
// Decode keys -> theta (float) into d_out[0:8192]
// =====================================================================
__global__ __launch_bounds__(256) void decode_kernel(const unsigned* __restrict__ keys,
                                                     float* __restrict__ theta) {
  int i = blockIdx.x * 256 + threadIdx.x;
  theta[i] = funkey(keys[i]);
}

// =====================================================================
// h1base[stage][b][c] = bias[c] + sum_k theta[b][k] * w1[k][c]   (no relu, no tail rows)
// 2 stages x 16 b x 512 c = 16384 outputs
// =====================================================================
__global__ __launch_bounds__(256) void h1base_kernel(
    const float* __restrict__ theta,
    const float* __restrict__ f1w1, const float* __restrict__ f1b1,
    const float* __restrict__ f2w1, const float* __restrict__ f2b1,
    float* __restrict__ h1b)
{
  int gid = blockIdx.x * 256 + threadIdx.x;
  int stage = gid >> 13;
  int rem = gid & 8191;
  int b = rem >> 9, c = rem & 511;
  const float* w = stage ? f2w1 : f1w1;
  float acc = stage ? f2b1[c] : f1b1[c];
  const float* th = theta + b * 512;
  #pragma unroll 8
  for (int k = 0; k < 512; ++k) acc += th[k] * w[(size_t)k * 512 + c];
  h1b[gid] = acc;
}

// =====================================================================
// Fused folding decoder: per block = 16 rows; both stages.
// =====================================================================
struct FoldSmem {
  float h1[16][512];      // 32 KB
  float h2c[16][132];     // 8.25 KB (pad 132 to spread banks; 528B row, 16B-aligned)
  float w3[3][512];       // 6 KB
  float b2s[512];         // 2 KB
  float ext[16][4];       // grid (stage1) / fold1 (stage2)
  float red[16][16][3];   // 3 KB layer-3 seg reduction
};

template <int NE>
__device__ __forceinline__ void fold_stage(FoldSmem& S, int t, int r0,
    const float* __restrict__ h1b_s,
    const float* __restrict__ w1,
    const float* __restrict__ w2, const float* __restrict__ b2,
    const float* __restrict__ w3, const float* __restrict__ b3,
    float* __restrict__ out_pc)
{
  // cooperative loads: w3 (transposed) + b2
  for (int i = t; i < 1536; i += 256) { int k = i / 3, j = i - k * 3; S.w3[j][k] = w3[i]; }
  for (int i = t; i < 512;  i += 256) S.b2s[i] = b2[i];
  __syncthreads();

  // phase A: h1[row][c] = relu(h1base[b][c] + sum_j ext[row][j]*w1[512+j][c])
  #pragma unroll
  for (int oi = 0; oi < 32; ++oi) {
    int o = oi * 256 + t;
    int row = o >> 9, c = o & 511;
    int r = r0 + row;
    int bb = r / MQ;
    float v = h1b_s[bb * 512 + c];
    v += S.ext[row][0] * w1[(size_t)512 * 512 + c];
    v += S.ext[row][1] * w1[(size_t)513 * 512 + c];
    if (NE == 3) v += S.ext[row][2] * w1[(size_t)514 * 512 + c];
    S.h1[row][c] = fmaxf(v, 0.f);
  }
  __syncthreads();

  // phase B: h2 = relu(h1 @ w2 + b2) in 4 col-chunks of 128; layer-3 partials fused
  const int ty = t >> 5, tx = t & 31;
  const int row0 = ty * 2;
  const int lrow = t >> 4, seg = t & 15;
  float p0 = 0.f, p1 = 0.f, p2 = 0.f;

  for (int cc = 0; cc < 4; ++cc) {
    float4 A0 = make_float4(0.f, 0.f, 0.f, 0.f);
    float4 A1 = make_float4(0.f, 0.f, 0.f, 0.f);
    const float* w2b = w2 + cc * 128 + (tx << 2);
    #pragma unroll 2
    for (int k = 0; k < 512; k += 4) {
      float4 ha = *(const float4*)&S.h1[row0][k];
      float4 hb = *(const float4*)&S.h1[row0 + 1][k];
      float4 q0 = *(const float4*)(w2b + (size_t)(k + 0) * 512);
      float4 q1 = *(const float4*)(w2b + (size_t)(k + 1) * 512);
      float4 q2 = *(const float4*)(w2b + (size_t)(k + 2) * 512);
      float4 q3 = *(const float4*)(w2b + (size_t)(k + 3) * 512);
      fma4(A0, ha.x, q0); fma4(A0, ha.y, q1); fma4(A0, ha.z, q2); fma4(A0, ha.w, q3);
      fma4(A1, hb.x, q0); fma4(A1, hb.y, q1); fma4(A1, hb.z, q2); fma4(A1, hb.w, q3);
    }
    const int c0 = cc * 128 + (tx << 2);
    float4 bias = *(const float4*)&S.b2s[c0];
    float4 r0v, r1v;
    r0v.x = fmaxf(A0.x + bias.x, 0.f); r0v.y = fmaxf(A0.y + bias.y, 0.f);
    r0v.z = fmaxf(A0.z + bias.z, 0.f); r0v.w = fmaxf(A0.w + bias.w, 0.f);
    r1v.x = fmaxf(A1.x + bias.x, 0.f); r1v.y = fmaxf(A1.y + bias.y, 0.f);
    r1v.z = fmaxf(A1.z + bias.z, 0.f); r1v.w = fmaxf(A1.w + bias.w, 0.f);
    *(float4*)&S.h2c[row0][tx << 2]     = r0v;
    *(float4*)&S.h2c[row0 + 1][tx << 2] = r1v;
    __syncthreads();
    // layer-3 partials: thread = (row, k-seg of 8)
    #pragma unroll
    for (int i = 0; i < 8; ++i) {
      float h = S.h2c[lrow][seg * 8 + i];
      int k = cc * 128 + seg * 8 + i;
      p0 += h * S.w3[0][k];
      p1 += h * S.w3[1][k];
      p2 += h * S.w3[2][k];
    }
    __syncthreads();
  }

  // phase C: reduce layer-3 partials over 16 segs
  S.red[lrow][seg][0] = p0; S.red[lrow][seg][1] = p1; S.red[lrow][seg][2] = p2;
  __syncthreads();
  if (t < 48) {
    int row = t / 3, j = t - row * 3;
    float v = b3[j];
    #pragma unroll
    for (int s = 0; s < 16; ++s) v += S.red[row][s][j];
    if (NE == 3) out_pc[(size_t)(r0 + row) * 3 + j] = v;   // final pc_out
    else         S.ext[row][j] = v;                        // fold1 -> next stage ext
  }
  __syncthreads();
}

__global__ __launch_bounds__(256) void fold_kernel(
    const float* __restrict__ grid2, const float* __restrict__ h1b,
    const float* __restrict__ f1w1, const float* __restrict__ f1w2, const float* __restrict__ f1b2,
    const float* __restrict__ f1w3, const float* __restrict__ f1b3,
    const float* __restrict__ f2w1, const float* __restrict__ f2w2, const float* __restrict__ f2b2,
    const float* __restrict__ f2w3, const float* __restrict__ f2b3,
    float* __restrict__ out_pc)
{
  __shared__ FoldSmem S;
  const int t = threadIdx.x;
  const int r0 = blockIdx.x * 16;
  if (t < 32) {
    int row = t >> 1, j = t & 1;
    int r = r0 + row;
    int bb = r / MQ; int m = r - bb * MQ;
    S.ext[row][j] = grid2[m * 2 + j];
  }
  // (sync inside fold_stage after coop loads covers ext init)
  fold_stage<2>(S, t, r0, h1b,        f1w1, f1w2, f1b2, f1w3, f1b3, nullptr);
  fold_stage<3>(S, t, r0, h1b + 8192, f2w1, f2w2, f2b2, f2w3, f2b3, out_pc);
}

// =====================================================================
// Chamfer A: for each (b,n): min over m of |a_n - b_m|^2 ; sum -> lacc[0]
// =====================================================================
__global__ __launch_bounds__(256) void chamA_kernel(const float* __restrict__ pts,
                                                    const float* __restrict__ pc,
                                                    float* __restrict__ lacc)
{
  __shared__ float sbx[MQ], sby[MQ], sbz[MQ];
  __shared__ float ssum[256];
  const int t = threadIdx.x;
  const int b = blockIdx.x >> 3;
  const float* pcb = pc + (size_t)b * (MQ * 3);
  for (int i = t; i < MQ * 3; i += 256) {
    float v = pcb[i];
    int m = i / 3, j = i - m * 3;
    if (j == 0) sbx[m] = v; else if (j == 1) sby[m] = v; else sbz[m] = v;
  }
  __syncthreads();

  const int n = ((blockIdx.x & 7) << 8) + t;
  float4 p = *(const float4*)(pts + ((size_t)b * NPTS + n) * 4);
  const float ax = p.x, ay = p.y, az = p.z + p.w;
  float q0 = 1e30f, q1 = 1e30f, q2 = 1e30f;
  for (int m = 0; m < MQ; m += 3) {
    { float dx = ax - sbx[m],   dy = ay - sby[m],   dz = az - sbz[m];
      q0 = fminf(q0, dx*dx + dy*dy + dz*dz); }
    { float dx = ax - sbx[m+1], dy = ay - sby[m+1], dz = az - sbz[m+1];
      q1 = fminf(q1, dx*dx + dy*dy + dz*dz); }
    { float dx = ax - sbx[m+2], dy = ay - sby[m+2], dz = az - sbz[m+2];
      q2 = fminf(q2, dx*dx + dy*dy + dz*dz); }
  }
  ssum[t] = fminf(q0, fminf(q1, q2));
  __syncthreads();
  for (int s = 128; s > 0; s >>= 1) { if (t < s) ssum[t] += ssum[t + s]; __syncthreads(); }
  if (t == 0) atomicAdd(lacc, ssum[0]);
}

// =====================================================================
// Chamfer B: for each (b,m): min over n ; sum -> lacc[1]
// =====================================================================
__global__ __launch_bounds__(256) void chamB_kernel(const float* __restrict__ pts,
                                                    const float* __restrict__ pc,
                                                    float* __restrict__ lacc)
{
  __shared__ float sax[NPTS], say[NPTS], saz[NPTS];
  __shared__ float ssum[256];
  const int t = threadIdx.x;
  const int b = blockIdx.x >> 3;
  for (int i = t; i < NPTS; i += 256) {
    float4 p = *(const float4*)(pts + ((size_t)b * NPTS + i) * 4);
    sax[i] = p.x; say[i] = p.y; saz[i] = p.z + p.w;
  }
  __syncthreads();

  const int m = ((blockIdx.x & 7) << 8) + t;
  const bool valid = (m < MQ);
  const int mc = valid ? m : (MQ - 1);
  const float bx = pc[(size_t)b * (MQ*3) + mc*3 + 0];
  const float by = pc[(size_t)b * (MQ*3) + mc*3 + 1];
  const float bz = pc[(size_t)b * (MQ*3) + mc*3 + 2];
  float q0 = 1e30f, q1 = 1e30f, q2 = 1e30f, q3 = 1e30f;
  for (int n = 0; n < NPTS; n += 4) {
    { float dx = sax[n]   - bx, dy = say[n]   - by, dz = saz[n]   - bz;
      q0 = fminf(q0, dx*dx + dy*dy + dz*dz); }
    { float dx = sax[n+1] - bx, dy = say[n+1] - by, dz = saz[n+1] - bz;
      q1 = fminf(q1, dx*dx + dy*dy + dz*dz); }
    { float dx = sax[n+2] - bx, dy = say[n+2] - by, dz = saz[n+2] - bz;
      q2 = fminf(q2, dx*dx + dy*dy + dz*dz); }
    { float dx = sax[n+3] - bx, dy = say[n+3] - by, dz = saz[n+3] - bz;
      q3 = fminf(q3, dx*dx + dy*dy + dz*dz); }
  }
  float best = fminf(fminf(q0, q1), fminf(q2, q3));
  ssum[t] = valid ? best : 0.f;
  __syncthreads();
  for (int s = 128; s > 0; s >>= 1) { if (t < s) ssum[t] += ssum[t + s]; __syncthreads(); }
  if (t == 0) atomicAdd(lacc + 1, ssum[0]);
}

__global__ void fin_kernel(const float* __restrict__ lacc, float* __restrict__ loss) {
  if (threadIdx.x == 0 && blockIdx.x == 0)
    loss[0] = lacc[0] * (1.0f / (NBATCH * NPTS)) + lacc[1] * (1.0f / (NBATCH * MQ));
}

// =====================================================================
extern "C" void kernel_launch(void* const* d_in, const int* in_sizes, int n_in,
                              void* d_out, int out_size, void* d_ws, size_t ws_size,
                              hipStream_t stream) {
  const float* pts  = (const float*)d_in[0];
  const float* ew1  = (const float*)d_in[1];
  const float* eb1  = (const float*)d_in[2];
  const float* ew2  = (const float*)d_in[3];
  const float* eb2  = (const float*)d_in[4];
  const float* ew3  = (const float*)d_in[5];
  const float* eb3  = (const float*)d_in[6];
  const float* f1w1 = (const float*)d_in[7];
  const float* f1b1 = (const float*)d_in[8];
  const float* f1w2 = (const float*)d_in[9];
  const float* f1b2 = (const float*)d_in[10];
  const float* f1w3 = (const float*)d_in[11];
  const float* f1b3 = (const float*)d_in[12];
  const float* f2w1 = (const float*)d_in[13];
  const float* f2b1 = (const float*)d_in[14];
  const float* f2w2 = (const float*)d_in[15];
  const float* f2b2 = (const float*)d_in[16];
  const float* f2w3 = (const float*)d_in[17];
  const float* f2b3 = (const float*)d_in[18];
  const float* grid2= (const float*)d_in[19];   // grid added LAST in setup_inputs

  float* out = (float*)d_out;
  unsigned* keys = (unsigned*)d_ws;                              // 8192 u32 = 32KB
  float* h1b  = (float*)((char*)d_ws + 32768);                   // 2*16*512 f32 = 64KB
  float* lacc = (float*)((char*)d_ws + 32768 + 65536);           // 2 f32

  hipMemsetAsync(d_ws, 0, 98432, stream);  // zero keys (=-inf encoded) + loss accum

  enc_kernel<<<512, 256, 0, stream>>>(pts, ew1, eb1, ew2, eb2, ew3, eb3, keys);
  decode_kernel<<<32, 256, 0, stream>>>(keys, out);              // theta -> d_out[0:8192]
  h1base_kernel<<<64, 256, 0, stream>>>(out, f1w1, f1b1, f2w1, f2b1, h1b);
  fold_kernel<<<2025, 256, 0, stream>>>(grid2, h1b,
                                        f1w1, f1w2, f1b2, f1w3, f1b3,
                                        f2w1, f2w2, f2b2, f2w3, f2b3,
                                        out + 8192);             // pc_out
  chamA_kernel<<<128, 256, 0, stream>>>(pts, out + 8192, lacc);
  chamB_kernel<<<128, 256, 0, stream>>>(pts, out + 8192, lacc);
  fin_kernel<<<1, 64, 0, stream>>>(lacc, out + 8192 + 97200);    // loss -> d_out[105392]
}

// Round 2
// 381.824 us; speedup vs baseline: 3.3098x; 3.3098x over previous
//
#include <hip/hip_runtime.h>

#define NBATCH 16
#define NPTS   2048
#define MQ     2025
#define CWDIM  512
#define NROWS  32400   // 16 * 2025

typedef __attribute__((ext_vector_type(8))) short bf16x8;
typedef __attribute__((ext_vector_type(4))) float f32x4;

// ---------- helpers ----------
__device__ __forceinline__ unsigned fkey(float f) {
  unsigned u = __float_as_uint(f);
  return (u & 0x80000000u) ? ~u : (u | 0x80000000u);
}
__device__ __forceinline__ float funkey(unsigned u) {
  unsigned v = (u & 0x80000000u) ? (u ^ 0x80000000u) : ~u;
  return __uint_as_float(v);
}
__device__ __forceinline__ void fma4(float4& a, float s, float4 w) {
  a.x += s * w.x; a.y += s * w.y; a.z += s * w.z; a.w += s * w.w;
}
__device__ __forceinline__ unsigned short f2bf(float f) {  // RNE f32->bf16
  unsigned u = __float_as_uint(f);
  u = (u + 0x7FFFu + ((u >> 16) & 1u)) >> 16;
  return (unsigned short)u;
}

// =====================================================================
// Encoder: per block = one batch x 64 points. 4->64->128->512, max over pts,
// atomicMax(uint-encoded) into keys[B*512].   (unchanged from R1 - passed)
// =====================================================================
__global__ __launch_bounds__(256) void enc_kernel(
    const float* __restrict__ pts,
    const float* __restrict__ w1, const float* __restrict__ b1,
    const float* __restrict__ w2, const float* __restrict__ b2,
    const float* __restrict__ w3, const float* __restrict__ b3,
    unsigned* __restrict__ keys)
{
  __shared__ float s_pts[64][4];
  __shared__ float s_w1[4][64];
  __shared__ float s_b1[64];
  __shared__ float s_b2[128];
  __shared__ float s_h1[64][64];
  __shared__ float s_h2[64][128];
  __shared__ float s_red[8][128];

  const int t  = threadIdx.x;
  const int b  = blockIdx.x >> 5;
  const int p0 = (blockIdx.x & 31) << 6;

  if (t < 64)
    *(float4*)&s_pts[t][0] = *(const float4*)(pts + ((size_t)b * NPTS + p0 + t) * 4);
  s_w1[t >> 6][t & 63] = w1[t];
  if (t < 64)  s_b1[t] = b1[t];
  if (t < 128) s_b2[t] = b2[t];
  __syncthreads();

  #pragma unroll
  for (int i = 0; i < 16; ++i) {
    int o = i * 256 + t;
    int p = o >> 6, c = o & 63;
    float acc = s_b1[c];
    #pragma unroll
    for (int k = 0; k < 4; ++k) acc += s_pts[p][k] * s_w1[k][c];
    s_h1[p][c] = fmaxf(acc, 0.f);
  }
  __syncthreads();

  const int ty = t >> 5, tx = t & 31;

  {
    const int c0 = tx << 2;
    float4 acc[8];
    #pragma unroll
    for (int i = 0; i < 8; ++i) acc[i] = make_float4(0.f, 0.f, 0.f, 0.f);
    for (int k = 0; k < 64; k += 4) {
      float4 q0 = *(const float4*)(w2 + (size_t)(k + 0) * 128 + c0);
      float4 q1 = *(const float4*)(w2 + (size_t)(k + 1) * 128 + c0);
      float4 q2 = *(const float4*)(w2 + (size_t)(k + 2) * 128 + c0);
      float4 q3 = *(const float4*)(w2 + (size_t)(k + 3) * 128 + c0);
      #pragma unroll
      for (int i = 0; i < 8; ++i) {
        float4 h = *(const float4*)&s_h1[ty * 8 + i][k];
        fma4(acc[i], h.x, q0); fma4(acc[i], h.y, q1);
        fma4(acc[i], h.z, q2); fma4(acc[i], h.w, q3);
      }
    }
    float4 bias = *(const float4*)&s_b2[c0];
    #pragma unroll
    for (int i = 0; i < 8; ++i) {
      float4 v;
      v.x = fmaxf(acc[i].x + bias.x, 0.f);
      v.y = fmaxf(acc[i].y + bias.y, 0.f);
      v.z = fmaxf(acc[i].z + bias.z, 0.f);
      v.w = fmaxf(acc[i].w + bias.w, 0.f);
      *(float4*)&s_h2[ty * 8 + i][c0] = v;
    }
  }
  __syncthreads();

  for (int cc = 0; cc < 4; ++cc) {
    const int gc0 = cc * 128 + (tx << 2);
    float4 acc[8];
    #pragma unroll
    for (int i = 0; i < 8; ++i) acc[i] = make_float4(0.f, 0.f, 0.f, 0.f);
    for (int k = 0; k < 128; k += 4) {
      float4 q0 = *(const float4*)(w3 + (size_t)(k + 0) * 512 + gc0);
      float4 q1 = *(const float4*)(w3 + (size_t)(k + 1) * 512 + gc0);
      float4 q2 = *(const float4*)(w3 + (size_t)(k + 2) * 512 + gc0);
      float4 q3 = *(const float4*)(w3 + (size_t)(k + 3) * 512 + gc0);
      #pragma unroll
      for (int i = 0; i < 8; ++i) {
        float4 h = *(const float4*)&s_h2[ty * 8 + i][k];
        fma4(acc[i], h.x, q0); fma4(acc[i], h.y, q1);
        fma4(acc[i], h.z, q2); fma4(acc[i], h.w, q3);
      }
    }
    float4 bias = *(const float4*)(b3 + gc0);
    float4 mx = acc[0];
    #pragma unroll
    for (int i = 1; i < 8; ++i) {
      mx.x = fmaxf(mx.x, acc[i].x); mx.y = fmaxf(mx.y, acc[i].y);
      mx.z = fmaxf(mx.z, acc[i].z); mx.w = fmaxf(mx.w, acc[i].w);
    }
    mx.x += bias.x; mx.y += bias.y; mx.z += bias.z; mx.w += bias.w;
    *(float4*)&s_red[ty][tx << 2] = mx;
    __syncthreads();
    if (t < 128) {
      float mm = s_red[0][t];
      #pragma unroll
      for (int g = 1; g < 8; ++g) mm = fmaxf(mm, s_red[g][t]);
      atomicMax(&keys[b * CWDIM + cc * 128 + t], fkey(mm));
    }
    __syncthreads();
  }
}

__global__ __launch_bounds__(256) void decode_kernel(const unsigned* __restrict__ keys,
                                                     float* __restrict__ theta) {
  int i = blockIdx.x * 256 + threadIdx.x;
  theta[i] = funkey(keys[i]);
}

// =====================================================================
// h1base[stage][b][c] = bias[c] + sum_k theta[b][k] * w1[k][c]
// =====================================================================
__global__ __launch_bounds__(256) void h1base_kernel(
    const float* __restrict__ theta,
    const float* __restrict__ f1w1, const float* __restrict__ f1b1,
    const float* __restrict__ f2w1, const float* __restrict__ f2b1,
    float* __restrict__ h1b)
{
  int gid = blockIdx.x * 256 + threadIdx.x;
  int stage = gid >> 13;
  int rem = gid & 8191;
  int b = rem >> 9, c = rem & 511;
  const float* w = stage ? f2w1 : f1w1;
  float acc = stage ? f2b1[c] : f1b1[c];
  const float* th = theta + b * 512;
  #pragma unroll 8
  for (int k = 0; k < 512; ++k) acc += th[k] * w[(size_t)k * 512 + c];
  h1b[gid] = acc;
}

// =====================================================================
// Transpose + convert fold layer-2 weights: w2T[n][k] = bf16(w2[k][n])
// =====================================================================
__global__ __launch_bounds__(256) void w2conv_kernel(
    const float* __restrict__ f1w2, const float* __restrict__ f2w2,
    unsigned short* __restrict__ w2T)
{
  __shared__ float tile[32][33];
  const int s  = blockIdx.x >> 8;
  const int ti = blockIdx.x & 255;
  const int kt = ti >> 4, nt = ti & 15;
  const float* src = s ? f2w2 : f1w2;
  unsigned short* dst = w2T + (size_t)s * 262144;
  const int tx = threadIdx.x & 31, ty = threadIdx.x >> 5;
  #pragma unroll
  for (int j = 0; j < 4; ++j)
    tile[ty + 8 * j][tx] = src[(size_t)(kt * 32 + ty + 8 * j) * 512 + nt * 32 + tx];
  __syncthreads();
  #pragma unroll
  for (int j = 0; j < 4; ++j) {
    int n = ty + 8 * j;
    dst[(size_t)(nt * 32 + n) * 512 + kt * 32 + tx] = f2bf(tile[tx][n]);
  }
}

// =====================================================================
// Fused MFMA folding decoder: 48 rows/block, 512 thr = 8 waves,
// wave w = rows 0..47 x cols [64w,64w+64). Both fold stages in one kernel.
// =====================================================================
struct Fold2Smem {
  unsigned short h1[48 * 512];   // 48 KB, XOR-swizzled bf16
  float red[8][48][3];           // 4.6 KB
  float ext[48][4];              // 768 B
};

template <int NE>
__device__ __forceinline__ void fold2_stage(Fold2Smem& S, int t, int r0,
    int b0, int b1, int bsplit,
    const float* __restrict__ h1bs,       // h1base for this stage (16x512)
    const float* __restrict__ w1,         // (CW+NE) x 512 fp32 (rows 512.. used)
    const unsigned short* __restrict__ w2T, // 512x512 bf16 [n][k]
    const float* __restrict__ b2g, const float* __restrict__ w3g,
    const float* __restrict__ b3g, float* __restrict__ out_pc)
{
  const int wv = t >> 6, lane = t & 63;

  // ---- phase A: h1[row][c] = relu(h1base + ext @ w1ext), bf16 swizzled LDS
  {
    const int cu = (t & 255) << 1;       // two cols per thread
    const int rbase = (t >> 8) * 24;     // rows 0..23 or 24..47
    const float b0a = h1bs[b0 * 512 + cu],     b0b = h1bs[b0 * 512 + cu + 1];
    const float b1a = h1bs[b1 * 512 + cu],     b1b = h1bs[b1 * 512 + cu + 1];
    const float w0a = w1[(size_t)512 * 512 + cu], w0b = w1[(size_t)512 * 512 + cu + 1];
    const float w1a = w1[(size_t)513 * 512 + cu], w1b = w1[(size_t)513 * 512 + cu + 1];
    float w2a = 0.f, w2b = 0.f;
    if (NE == 3) { w2a = w1[(size_t)514 * 512 + cu]; w2b = w1[(size_t)514 * 512 + cu + 1]; }
    #pragma unroll 4
    for (int rr = 0; rr < 24; ++rr) {
      const int row = rbase + rr;
      const bool hi = (r0 + row) >= bsplit;
      const float e0 = S.ext[row][0], e1 = S.ext[row][1];
      float va = (hi ? b1a : b0a) + e0 * w0a + e1 * w1a;
      float vb = (hi ? b1b : b0b) + e0 * w0b + e1 * w1b;
      if (NE == 3) { const float e2 = S.ext[row][2]; va += e2 * w2a; vb += e2 * w2b; }
      va = fmaxf(va, 0.f); vb = fmaxf(vb, 0.f);
      unsigned byte = ((unsigned)row << 10) + ((unsigned)cu << 1);
      byte ^= ((unsigned)(row & 7)) << 4;
      unsigned pack = (unsigned)f2bf(va) | ((unsigned)f2bf(vb) << 16);
      *(unsigned*)&S.h1[byte >> 1] = pack;
    }
  }
  __syncthreads();

  // ---- phase B: h2 = relu(h1 @ w2 + b2) via MFMA; 3 row-frags x 4 col-frags
  const int kgrp = (lane >> 4) * 8;
  const int l15  = lane & 15;
  f32x4 acc[3][4];
  #pragma unroll
  for (int m = 0; m < 3; ++m)
    #pragma unroll
    for (int n = 0; n < 4; ++n) acc[m][n] = (f32x4){0.f, 0.f, 0.f, 0.f};

  const unsigned short* wbase = w2T + (size_t)(wv * 64 + l15) * 512 + kgrp;
  bf16x8 bcur[4], bnxt[4];
  #pragma unroll
  for (int n = 0; n < 4; ++n) bcur[n] = *(const bf16x8*)(wbase + (size_t)(16 * n) * 512);

  for (int kk = 0; kk < 512; kk += 32) {
    if (kk < 480) {
      #pragma unroll
      for (int n = 0; n < 4; ++n)
        bnxt[n] = *(const bf16x8*)(wbase + (size_t)(16 * n) * 512 + (kk + 32));
    }
    bf16x8 a[3];
    #pragma unroll
    for (int m = 0; m < 3; ++m) {
      const int row = 16 * m + l15;
      unsigned byte = ((unsigned)row << 10) + ((unsigned)(kk + kgrp) << 1);
      byte ^= ((unsigned)(row & 7)) << 4;
      a[m] = *(const bf16x8*)&S.h1[byte >> 1];
    }
    #pragma unroll
    for (int m = 0; m < 3; ++m)
      #pragma unroll
      for (int n = 0; n < 4; ++n)
        acc[m][n] = __builtin_amdgcn_mfma_f32_16x16x32_bf16(a[m], bcur[n], acc[m][n], 0, 0, 0);
    #pragma unroll
    for (int n = 0; n < 4; ++n) bcur[n] = bnxt[n];
  }

  // ---- layer 3 in-register: p[row][j] = sum_c relu(acc+b2[c]) * w3[c][j]
  float p[3][4][3];
  #pragma unroll
  for (int m = 0; m < 3; ++m)
    #pragma unroll
    for (int j4 = 0; j4 < 4; ++j4)
      #pragma unroll
      for (int jj = 0; jj < 3; ++jj) p[m][j4][jj] = 0.f;

  #pragma unroll
  for (int n = 0; n < 4; ++n) {
    const int c = wv * 64 + 16 * n + l15;
    const float b2c = b2g[c];
    const float w30 = w3g[c * 3 + 0], w31 = w3g[c * 3 + 1], w32 = w3g[c * 3 + 2];
    #pragma unroll
    for (int m = 0; m < 3; ++m) {
      #pragma unroll
      for (int j4 = 0; j4 < 4; ++j4) {
        const float h = fmaxf(acc[m][n][j4] + b2c, 0.f);
        p[m][j4][0] += h * w30; p[m][j4][1] += h * w31; p[m][j4][2] += h * w32;
      }
    }
  }
  // butterfly-reduce over the 16 cols held by lanes with equal lane>>4
  #pragma unroll
  for (int m = 0; m < 3; ++m)
    #pragma unroll
    for (int j4 = 0; j4 < 4; ++j4)
      #pragma unroll
      for (int jj = 0; jj < 3; ++jj) {
        float v = p[m][j4][jj];
        v += __shfl_xor(v, 1); v += __shfl_xor(v, 2);
        v += __shfl_xor(v, 4); v += __shfl_xor(v, 8);
        p[m][j4][jj] = v;
      }
  if (l15 == 0) {
    const int rbase = (lane >> 4) * 4;
    #pragma unroll
    for (int m = 0; m < 3; ++m)
      #pragma unroll
      for (int j4 = 0; j4 < 4; ++j4) {
        const int row = 16 * m + rbase + j4;
        S.red[wv][row][0] = p[m][j4][0];
        S.red[wv][row][1] = p[m][j4][1];
        S.red[wv][row][2] = p[m][j4][2];
      }
  }
  __syncthreads();

  if (t < 144) {
    const int row = t / 3, jj = t - row * 3;
    float v = b3g[jj];
    #pragma unroll
    for (int w = 0; w < 8; ++w) v += S.red[w][row][jj];
    if (NE == 2) S.ext[row][jj] = v;                       // fold1 -> stage-2 ext
    else         out_pc[(size_t)(r0 + row) * 3 + jj] = v;  // final pc_out
  }
  __syncthreads();
}

__global__ __launch_bounds__(512, 2) void fold2_kernel(
    const float* __restrict__ grid2, const float* __restrict__ h1b,
    const unsigned short* __restrict__ w2T,
    const float* __restrict__ f1w1, const float* __restrict__ f1b2,
    const float* __restrict__ f1w3, const float* __restrict__ f1b3,
    const float* __restrict__ f2w1, const float* __restrict__ f2b2,
    const float* __restrict__ f2w3, const float* __restrict__ f2b3,
    float* __restrict__ out_pc)
{
  __shared__ Fold2Smem S;
  const int t  = threadIdx.x;
  const int r0 = blockIdx.x * 48;                // 675 * 48 = 32400 exactly
  const int b0 = r0 / MQ;
  const int bsplit = (b0 + 1) * MQ;
  const int b1 = min(b0 + 1, NBATCH - 1);

  if (t < 96) {
    const int row = t >> 1, j = t & 1;
    const int r = r0 + row;
    const int bb = r / MQ;
    const int m = r - bb * MQ;
    S.ext[row][j] = grid2[m * 2 + j];
  }
  __syncthreads();

  fold2_stage<2>(S, t, r0, b0, b1, bsplit, h1b,        f1w1, w2T,
                 f1b2, f1w3, f1b3, nullptr);
  fold2_stage<3>(S, t, r0, b0, b1, bsplit, h1b + 8192, f2w1, w2T + 262144,
                 f2b2, f2w3, f2b3, out_pc);
}

// =====================================================================
// Chamfer A: min over m for each (b,n). 512 blocks, 4 threads per point.
// =====================================================================
__global__ __launch_bounds__(256) void chamA_kernel(const float* __restrict__ pts,
                                                    const float* __restrict__ pc,
                                                    float* __restrict__ lacc)
{
  __shared__ float sbx[MQ], sby[MQ], sbz[MQ];
  __shared__ float smin[64];
  const int t = threadIdx.x;
  const int b = blockIdx.x >> 5;
  const int n0 = (blockIdx.x & 31) << 6;
  const float* pcb = pc + (size_t)b * (MQ * 3);
  for (int i = t; i < MQ * 3; i += 256) {
    float v = pcb[i];
    int m = i / 3, j = i - m * 3;
    if (j == 0) sbx[m] = v; else if (j == 1) sby[m] = v; else sbz[m] = v;
  }
  __syncthreads();

  const int p = t >> 2, q = t & 3;
  const int n = n0 + p;
  float4 pt = *(const float4*)(pts + ((size_t)b * NPTS + n) * 4);
  const float ax = pt.x, ay = pt.y, az = pt.z + pt.w;
  float q0 = 1e30f, q1 = 1e30f;
  int m = q;
  for (; m + 4 < MQ; m += 8) {
    { float dx = ax - sbx[m],     dy = ay - sby[m],     dz = az - sbz[m];
      q0 = fminf(q0, dx * dx + dy * dy + dz * dz); }
    { float dx = ax - sbx[m + 4], dy = ay - sby[m + 4], dz = az - sbz[m + 4];
      q1 = fminf(q1, dx * dx + dy * dy + dz * dz); }
  }
  if (m < MQ) {
    float dx = ax - sbx[m], dy = ay - sby[m], dz = az - sbz[m];
    q0 = fminf(q0, dx * dx + dy * dy + dz * dz);
  }
  float v = fminf(q0, q1);
  v = fminf(v, __shfl_xor(v, 1));
  v = fminf(v, __shfl_xor(v, 2));
  if (q == 0) smin[p] = v;
  __syncthreads();
  if (t < 32) {
    float s = smin[t] + smin[t + 32];
    for (int off = 16; off > 0; off >>= 1) s += __shfl_down(s, off, 32);
    if (t == 0) atomicAdd(lacc, s);
  }
}

// =====================================================================
// Chamfer B: min over n for each (b,m). 512 blocks, 4 threads per point.
// =====================================================================
__global__ __launch_bounds__(256) void chamB_kernel(const float* __restrict__ pts,
                                                    const float* __restrict__ pc,
                                                    float* __restrict__ lacc)
{
  __shared__ float sax[NPTS], say[NPTS], saz[NPTS];
  __shared__ float smin[64];
  const int t = threadIdx.x;
  const int b = blockIdx.x >> 5;
  const int m0 = (blockIdx.x & 31) << 6;
  for (int i = t; i < NPTS; i += 256) {
    float4 pp = *(const float4*)(pts + ((size_t)b * NPTS + i) * 4);
    sax[i] = pp.x; say[i] = pp.y; saz[i] = pp.z + pp.w;
  }
  __syncthreads();

  const int p = t >> 2, q = t & 3;
  const int m = m0 + p;
  const bool valid = (m < MQ);
  const int mc = valid ? m : (MQ - 1);
  const float bx = pc[(size_t)b * (MQ * 3) + mc * 3 + 0];
  const float by = pc[(size_t)b * (MQ * 3) + mc * 3 + 1];
  const float bz = pc[(size_t)b * (MQ * 3) + mc * 3 + 2];
  float q0 = 1e30f, q1 = 1e30f;
  for (int i = 0; i < 256; ++i) {
    int n = q + 8 * i;
    { float dx = sax[n]     - bx, dy = say[n]     - by, dz = saz[n]     - bz;
      q0 = fminf(q0, dx * dx + dy * dy + dz * dz); }
    { float dx = sax[n + 4] - bx, dy = say[n + 4] - by, dz = saz[n + 4] - bz;
      q1 = fminf(q1, dx * dx + dy * dy + dz * dz); }
  }
  float v = fminf(q0, q1);
  v = fminf(v, __shfl_xor(v, 1));
  v = fminf(v, __shfl_xor(v, 2));
  if (q == 0) smin[p] = valid ? v : 0.f;
  __syncthreads();
  if (t < 32) {
    float s = smin[t] + smin[t + 32];
    for (int off = 16; off > 0; off >>= 1) s += __shfl_down(s, off, 32);
    if (t == 0) atomicAdd(lacc + 1, s);
  }
}

__global__ void fin_kernel(const float* __restrict__ lacc, float* __restrict__ loss) {
  if (threadIdx.x == 0 && blockIdx.x == 0)
    loss[0] = lacc[0] * (1.0f / (NBATCH * NPTS)) + lacc[1] * (1.0f / (NBATCH * MQ));
}

// =====================================================================
extern "C" void kernel_launch(void* const* d_in, const int* in_sizes, int n_in,
                              void* d_out, int out_size, void* d_ws, size_t ws_size,
                              hipStream_t stream) {
  const float* pts  = (const float*)d_in[0];
  const float* ew1  = (const float*)d_in[1];
  const float* eb1  = (const float*)d_in[2];
  const float* ew2  = (const float*)d_in[3];
  const float* eb2  = (const float*)d_in[4];
  const float* ew3  = (const float*)d_in[5];
  const float* eb3  = (const float*)d_in[6];
  const float* f1w1 = (const float*)d_in[7];
  const float* f1b1 = (const float*)d_in[8];
  const float* f1w2 = (const float*)d_in[9];
  const float* f1b2 = (const float*)d_in[10];
  const float* f1w3 = (const float*)d_in[11];
  const float* f1b3 = (const float*)d_in[12];
  const float* f2w1 = (const float*)d_in[13];
  const float* f2b1 = (const float*)d_in[14];
  const float* f2w2 = (const float*)d_in[15];
  const float* f2b2 = (const float*)d_in[16];
  const float* f2w3 = (const float*)d_in[17];
  const float* f2b3 = (const float*)d_in[18];
  const float* grid2= (const float*)d_in[19];

  float* out = (float*)d_out;
  unsigned* keys       = (unsigned*)d_ws;                          // 32768 B
  float* lacc          = (float*)((char*)d_ws + 32768);            // 8 B (pad 256)
  float* h1b           = (float*)((char*)d_ws + 33024);            // 65536 B
  unsigned short* w2T  = (unsigned short*)((char*)d_ws + 98560);   // 1 MB bf16

  hipMemsetAsync(d_ws, 0, 33024, stream);   // keys (= -inf keys) + lacc

  enc_kernel<<<512, 256, 0, stream>>>(pts, ew1, eb1, ew2, eb2, ew3, eb3, keys);
  decode_kernel<<<32, 256, 0, stream>>>(keys, out);                 // theta
  h1base_kernel<<<64, 256, 0, stream>>>(out, f1w1, f1b1, f2w1, f2b1, h1b);
  w2conv_kernel<<<512, 256, 0, stream>>>(f1w2, f2w2, w2T);
  fold2_kernel<<<675, 512, 0, stream>>>(grid2, h1b, w2T,
                                        f1w1, f1b2, f1w3, f1b3,
                                        f2w1, f2b2, f2w3, f2b3,
                                        out + 8192);                // pc_out
  chamA_kernel<<<512, 256, 0, stream>>>(pts, out + 8192, lacc);
  chamB_kernel<<<512, 256, 0, stream>>>(pts, out + 8192, lacc);
  fin_kernel<<<1, 64, 0, stream>>>(lacc, out + 8192 + 97200);       // loss
}

// Round 3
// 332.678 us; speedup vs baseline: 3.7987x; 1.1477x over previous
//
#include <hip/hip_runtime.h>

#define NBATCH 16
#define NPTS   2048
#define MQ     2025
#define CWDIM  512

typedef __attribute__((ext_vector_type(8))) short bf16x8;
typedef __attribute__((ext_vector_type(4))) float f32x4;

// ---------- helpers ----------
__device__ __forceinline__ unsigned fkey(float f) {
  unsigned u = __float_as_uint(f);
  return (u & 0x80000000u) ? ~u : (u | 0x80000000u);
}
__device__ __forceinline__ float funkey(unsigned u) {
  unsigned v = (u & 0x80000000u) ? (u ^ 0x80000000u) : ~u;
  return __uint_as_float(v);
}
__device__ __forceinline__ unsigned short f2bf(float f) {  // RNE f32->bf16
  unsigned u = __float_as_uint(f);
  u = (u + 0x7FFFu + ((u >> 16) & 1u)) >> 16;
  return (unsigned short)u;
}

// =====================================================================
// Generic 32x32 transpose + f32->bf16 convert.
// blocks: [0,256) f1w2 512x512 | [256,512) f2w2 | [512,520) ew2 64x128 |
//         [520,584) ew3 128x512
// =====================================================================
__global__ __launch_bounds__(256) void tconv_kernel(
    const float* __restrict__ f1w2, const float* __restrict__ f2w2,
    const float* __restrict__ ew2,  const float* __restrict__ ew3,
    unsigned short* __restrict__ w2T, unsigned short* __restrict__ ew2T,
    unsigned short* __restrict__ ew3T)
{
  __shared__ float tile[32][33];
  const int blk = blockIdx.x;
  const float* src; unsigned short* dst; int K, N, tidx;
  if (blk < 256)      { src = f1w2; dst = w2T;            K = 512; N = 512; tidx = blk; }
  else if (blk < 512) { src = f2w2; dst = w2T + 262144;   K = 512; N = 512; tidx = blk - 256; }
  else if (blk < 520) { src = ew2;  dst = ew2T;           K = 64;  N = 128; tidx = blk - 512; }
  else                { src = ew3;  dst = ew3T;           K = 128; N = 512; tidx = blk - 520; }
  const int ntn = N >> 5;
  const int kt = tidx / ntn, nt = tidx - kt * ntn;
  const int tx = threadIdx.x & 31, ty = threadIdx.x >> 5;
  #pragma unroll
  for (int j = 0; j < 4; ++j)
    tile[ty + 8 * j][tx] = src[(size_t)(kt * 32 + ty + 8 * j) * N + nt * 32 + tx];
  __syncthreads();
  #pragma unroll
  for (int j = 0; j < 4; ++j)
    dst[(size_t)(nt * 32 + ty + 8 * j) * K + kt * 32 + tx] = f2bf(tile[tx][ty + 8 * j]);
}

// =====================================================================
// Encoder (MFMA): block = 64 points, 512 thr = 8 waves.
// layer1 VALU (K=4) -> h1s LDS bf16; layer2 MFMA 64x128 (K=64);
// layer3 MFMA 64x512 (K=128) + in-register max-pool -> atomicMax keys.
// =====================================================================
__global__ __launch_bounds__(512, 4) void enc2_kernel(
    const float* __restrict__ pts,
    const float* __restrict__ ew1, const float* __restrict__ eb1,
    const unsigned short* __restrict__ ew2T, const float* __restrict__ eb2,
    const unsigned short* __restrict__ ew3T, const float* __restrict__ eb3,
    unsigned* __restrict__ keys)
{
  __shared__ unsigned short h1s[64 * 64];    // row stride 128 B, swz (row&7)<<4
  __shared__ unsigned short h2s[64 * 128];   // row stride 256 B, swz (row&7)<<4
  __shared__ float s_pts[64][4];
  const int t = threadIdx.x;
  const int b = blockIdx.x >> 5, p0 = (blockIdx.x & 31) << 6;
  if (t < 64)
    *(float4*)&s_pts[t][0] = *(const float4*)(pts + ((size_t)b * NPTS + p0 + t) * 4);
  __syncthreads();

  // layer 1
  {
    const int c = t & 63;
    const float w0 = ew1[c], w1 = ew1[64 + c], w2 = ew1[128 + c], w3 = ew1[192 + c];
    const float bb = eb1[c];
    #pragma unroll
    for (int i = 0; i < 8; ++i) {
      const int p = i * 8 + (t >> 6);
      float acc = bb + s_pts[p][0] * w0 + s_pts[p][1] * w1 + s_pts[p][2] * w2 + s_pts[p][3] * w3;
      unsigned byte = ((unsigned)p << 7) + ((unsigned)c << 1);
      byte ^= ((unsigned)(p & 7)) << 4;
      h1s[byte >> 1] = f2bf(fmaxf(acc, 0.f));
    }
  }
  __syncthreads();

  const int wv = t >> 6, lane = t & 63, l15 = lane & 15, hi = lane >> 4;

  // layer 2: wave -> cols 16*wv .. +16
  {
    f32x4 acc[4];
    #pragma unroll
    for (int m = 0; m < 4; ++m) acc[m] = (f32x4){0.f, 0.f, 0.f, 0.f};
    const int col = 16 * wv + l15;
    #pragma unroll
    for (int kk = 0; kk < 64; kk += 32) {
      bf16x8 bv = *(const bf16x8*)(ew2T + (size_t)col * 64 + kk + hi * 8);
      #pragma unroll
      for (int m = 0; m < 4; ++m) {
        const int row = 16 * m + l15;
        unsigned byte = ((unsigned)row << 7) + ((unsigned)((kk + hi * 8)) << 1);
        byte ^= ((unsigned)(row & 7)) << 4;
        bf16x8 av = *(const bf16x8*)&h1s[byte >> 1];
        acc[m] = __builtin_amdgcn_mfma_f32_16x16x32_bf16(av, bv, acc[m], 0, 0, 0);
      }
    }
    const float b2c = eb2[col];
    #pragma unroll
    for (int m = 0; m < 4; ++m)
      #pragma unroll
      for (int r = 0; r < 4; ++r) {
        const int row = 16 * m + hi * 4 + r;
        unsigned byte = ((unsigned)row << 8) + ((unsigned)col << 1);
        byte ^= ((unsigned)(row & 7)) << 4;
        h2s[byte >> 1] = f2bf(fmaxf(acc[m][r] + b2c, 0.f));
      }
  }
  __syncthreads();

  // layer 3: wave -> cols 64*wv + 16n + l15, K=128, then max over 64 rows
  {
    f32x4 acc[4][4];
    #pragma unroll
    for (int m = 0; m < 4; ++m)
      #pragma unroll
      for (int n = 0; n < 4; ++n) acc[m][n] = (f32x4){0.f, 0.f, 0.f, 0.f};
    #pragma unroll
    for (int kk = 0; kk < 128; kk += 32) {
      bf16x8 av[4];
      #pragma unroll
      for (int m = 0; m < 4; ++m) {
        const int row = 16 * m + l15;
        unsigned byte = ((unsigned)row << 8) + ((unsigned)(kk + hi * 8) << 1);
        byte ^= ((unsigned)(row & 7)) << 4;
        av[m] = *(const bf16x8*)&h2s[byte >> 1];
      }
      #pragma unroll
      for (int n = 0; n < 4; ++n) {
        const int col = 64 * wv + 16 * n + l15;
        bf16x8 bv = *(const bf16x8*)(ew3T + (size_t)col * 128 + kk + hi * 8);
        #pragma unroll
        for (int m = 0; m < 4; ++m)
          acc[m][n] = __builtin_amdgcn_mfma_f32_16x16x32_bf16(av[m], bv, acc[m][n], 0, 0, 0);
      }
    }
    #pragma unroll
    for (int n = 0; n < 4; ++n) {
      const int col = 64 * wv + 16 * n + l15;
      float mx = -1e30f;
      #pragma unroll
      for (int m = 0; m < 4; ++m)
        #pragma unroll
        for (int r = 0; r < 4; ++r) mx = fmaxf(mx, acc[m][n][r]);
      mx = fmaxf(mx, __shfl_xor(mx, 16));
      mx = fmaxf(mx, __shfl_xor(mx, 32));
      if (hi == 0) atomicMax(&keys[b * CWDIM + col], fkey(mx + eb3[col]));
    }
  }
}

__global__ __launch_bounds__(256) void decode_kernel(const unsigned* __restrict__ keys,
                                                     float* __restrict__ theta) {
  int i = blockIdx.x * 256 + threadIdx.x;
  theta[i] = funkey(keys[i]);
}

// =====================================================================
// h1base split-K x2: atomicAdd partials (h1b pre-zeroed by memset)
// =====================================================================
__global__ __launch_bounds__(256) void h1base_kernel(
    const float* __restrict__ theta,
    const float* __restrict__ f1w1, const float* __restrict__ f1b1,
    const float* __restrict__ f2w1, const float* __restrict__ f2b1,
    float* __restrict__ h1b)
{
  int gid = blockIdx.x * 256 + threadIdx.x;   // 32768
  int half = gid >> 14;
  int rem = gid & 16383;
  int stage = rem >> 13, bb = (rem >> 9) & 15, c = rem & 511;
  const float* w = stage ? f2w1 : f1w1;
  float acc = 0.f;
  if (half == 0) acc = stage ? f2b1[c] : f1b1[c];
  const float* th = theta + bb * 512 + half * 256;
  const float* wp = w + (size_t)(half * 256) * 512 + c;
  #pragma unroll 8
  for (int k = 0; k < 256; ++k) acc += th[k] * wp[(size_t)k * 512];
  atomicAdd(&h1b[rem], acc);
}

// =====================================================================
// Fused MFMA folding decoder: 48 rows/block, 8 waves; both stages.
// =====================================================================
struct Fold2Smem {
  unsigned short h1[48 * 512];     // 49152 B, swz (row&7)<<4
  float red2[8 * 48 * 3 * 4];      // 18432 B  [wv][row][jj][pi]
  float ext[48][4];
};

template <int NE>
__device__ __forceinline__ void fold2_stage(Fold2Smem& S, int t, int r0,
    int b0, int b1, int bsplit,
    const float* __restrict__ h1bs,
    const float* __restrict__ w1,
    const unsigned short* __restrict__ w2T,
    const float* __restrict__ b2g, const float* __restrict__ w3g,
    const float* __restrict__ b3g, float* __restrict__ out_pc)
{
  const int wv = t >> 6, lane = t & 63, l15 = lane & 15, hi = lane >> 4;

  // ---- phase A: h1[row][c] = relu(h1base + ext @ w1ext) -> bf16 swizzled LDS
  {
    const int cu = (t & 255) << 1;
    const int rbase = (t >> 8) * 24;
    const float b0a = h1bs[b0 * 512 + cu],        b0b = h1bs[b0 * 512 + cu + 1];
    const float b1a = h1bs[b1 * 512 + cu],        b1b = h1bs[b1 * 512 + cu + 1];
    const float w0a = w1[(size_t)512 * 512 + cu], w0b = w1[(size_t)512 * 512 + cu + 1];
    const float w1a = w1[(size_t)513 * 512 + cu], w1b = w1[(size_t)513 * 512 + cu + 1];
    float w2a = 0.f, w2b = 0.f;
    if (NE == 3) { w2a = w1[(size_t)514 * 512 + cu]; w2b = w1[(size_t)514 * 512 + cu + 1]; }
    #pragma unroll 4
    for (int rr = 0; rr < 24; ++rr) {
      const int row = rbase + rr;
      const bool hib = (r0 + row) >= bsplit;
      const float e0 = S.ext[row][0], e1 = S.ext[row][1];
      float va = (hib ? b1a : b0a) + e0 * w0a + e1 * w1a;
      float vb = (hib ? b1b : b0b) + e0 * w0b + e1 * w1b;
      if (NE == 3) { const float e2 = S.ext[row][2]; va += e2 * w2a; vb += e2 * w2b; }
      va = fmaxf(va, 0.f); vb = fmaxf(vb, 0.f);
      unsigned byte = ((unsigned)row << 10) + ((unsigned)cu << 1);
      byte ^= ((unsigned)(row & 7)) << 4;
      unsigned pack = (unsigned)f2bf(va) | ((unsigned)f2bf(vb) << 16);
      *(unsigned*)&S.h1[byte >> 1] = pack;
    }
  }
  __syncthreads();

  // ---- phase B: h2 = relu(h1 @ w2 + b2) via MFMA, 2-deep B prefetch
  f32x4 acc[3][4];
  #pragma unroll
  for (int m = 0; m < 3; ++m)
    #pragma unroll
    for (int n = 0; n < 4; ++n) acc[m][n] = (f32x4){0.f, 0.f, 0.f, 0.f};

  const unsigned short* wb = w2T + (size_t)(wv * 64 + l15) * 512 + hi * 8;
  bf16x8 B0[4], B1[4];
  #pragma unroll
  for (int n = 0; n < 4; ++n) B0[n] = *(const bf16x8*)(wb + (size_t)(16 * n) * 512);
  #pragma unroll
  for (int n = 0; n < 4; ++n) B1[n] = *(const bf16x8*)(wb + (size_t)(16 * n) * 512 + 32);

  for (int kk = 0; kk < 512; kk += 32) {
    bf16x8 B2[4];
    if (kk < 448) {
      #pragma unroll
      for (int n = 0; n < 4; ++n)
        B2[n] = *(const bf16x8*)(wb + (size_t)(16 * n) * 512 + kk + 64);
    }
    bf16x8 a[3];
    #pragma unroll
    for (int m = 0; m < 3; ++m) {
      const int row = 16 * m + l15;
      unsigned byte = ((unsigned)row << 10) + ((unsigned)((kk + hi * 8)) << 1);
      byte ^= ((unsigned)(row & 7)) << 4;
      a[m] = *(const bf16x8*)&S.h1[byte >> 1];
    }
    #pragma unroll
    for (int m = 0; m < 3; ++m)
      #pragma unroll
      for (int n = 0; n < 4; ++n)
        acc[m][n] = __builtin_amdgcn_mfma_f32_16x16x32_bf16(a[m], B0[n], acc[m][n], 0, 0, 0);
    #pragma unroll
    for (int n = 0; n < 4; ++n) { B0[n] = B1[n]; B1[n] = B2[n]; }
  }

  // ---- layer 3 in-register + lite reduce
  float p[3][4][3];
  #pragma unroll
  for (int m = 0; m < 3; ++m)
    #pragma unroll
    for (int r = 0; r < 4; ++r)
      #pragma unroll
      for (int jj = 0; jj < 3; ++jj) p[m][r][jj] = 0.f;

  #pragma unroll
  for (int n = 0; n < 4; ++n) {
    const int c = wv * 64 + 16 * n + l15;
    const float b2c = b2g[c];
    const float w30 = w3g[c * 3 + 0], w31 = w3g[c * 3 + 1], w32 = w3g[c * 3 + 2];
    #pragma unroll
    for (int m = 0; m < 3; ++m)
      #pragma unroll
      for (int r = 0; r < 4; ++r) {
        const float h = fmaxf(acc[m][n][r] + b2c, 0.f);
        p[m][r][0] += h * w30; p[m][r][1] += h * w31; p[m][r][2] += h * w32;
      }
  }
  #pragma unroll
  for (int m = 0; m < 3; ++m)
    #pragma unroll
    for (int r = 0; r < 4; ++r)
      #pragma unroll
      for (int jj = 0; jj < 3; ++jj) {
        float v = p[m][r][jj];
        v += __shfl_xor(v, 1); v += __shfl_xor(v, 2);
        p[m][r][jj] = v;
      }
  if ((l15 & 3) == 0) {
    const int pi = l15 >> 2;
    #pragma unroll
    for (int m = 0; m < 3; ++m)
      #pragma unroll
      for (int r = 0; r < 4; ++r) {
        const int row = 16 * m + hi * 4 + r;
        #pragma unroll
        for (int jj = 0; jj < 3; ++jj)
          S.red2[(((wv * 48) + row) * 3 + jj) * 4 + pi] = p[m][r][jj];
      }
  }
  __syncthreads();

  if (t < 144) {
    const int row = t / 3, jj = t - (t / 3) * 3;
    float vs = b3g[jj];
    #pragma unroll
    for (int w = 0; w < 8; ++w) {
      float4 qv = *(const float4*)&S.red2[((w * 48 + row) * 3 + jj) * 4];
      vs += qv.x + qv.y + qv.z + qv.w;
    }
    if (NE == 2) S.ext[row][jj] = vs;
    else         out_pc[(size_t)(r0 + row) * 3 + jj] = vs;
  }
  __syncthreads();
}

__global__ __launch_bounds__(512, 4) void fold2_kernel(
    const float* __restrict__ grid2, const float* __restrict__ h1b,
    const unsigned short* __restrict__ w2T,
    const float* __restrict__ f1w1, const float* __restrict__ f1b2,
    const float* __restrict__ f1w3, const float* __restrict__ f1b3,
    const float* __restrict__ f2w1, const float* __restrict__ f2b2,
    const float* __restrict__ f2w3, const float* __restrict__ f2b3,
    float* __restrict__ out_pc)
{
  __shared__ Fold2Smem S;
  const int t  = threadIdx.x;
  const int r0 = blockIdx.x * 48;               // 675 * 48 = 32400
  const int b0 = r0 / MQ;
  const int bsplit = (b0 + 1) * MQ;
  const int b1 = min(b0 + 1, NBATCH - 1);

  if (t < 96) {
    const int row = t >> 1, j = t & 1;
    const int r = r0 + row;
    const int bb = r / MQ;
    const int m = r - bb * MQ;
    S.ext[row][j] = grid2[m * 2 + j];
  }
  __syncthreads();

  fold2_stage<2>(S, t, r0, b0, b1, bsplit, h1b,        f1w1, w2T,
                 f1b2, f1w3, f1b3, nullptr);
  fold2_stage<3>(S, t, r0, b0, b1, bsplit, h1b + 8192, f2w1, w2T + 262144,
                 f2b2, f2w3, f2b3, out_pc);
}

// =====================================================================
// Chamfer A: min over m for each (b,n). 512 blocks, 64 pts/block,
// 4 pts/thread, 16 threads share the m-sweep via float4 LDS reads.
// =====================================================================
__global__ __launch_bounds__(256) void chamA_kernel(const float* __restrict__ pts,
                                                    const float* __restrict__ pc,
                                                    float* __restrict__ lacc)
{
  __shared__ float sbx[2048], sby[2048], sbz[2048];
  const int t = threadIdx.x;
  const int b = blockIdx.x >> 5;
  const int n0 = (blockIdx.x & 31) << 6;
  const float* pcb = pc + (size_t)b * (MQ * 3);
  for (int i = t; i < MQ * 3; i += 256) {
    float v = pcb[i];
    int m = i / 3, j = i - m * 3;
    if (j == 0) sbx[m] = v; else if (j == 1) sby[m] = v; else sbz[m] = v;
  }
  for (int i = MQ + t; i < 2048; i += 256) { sbx[i] = 1e30f; sby[i] = 1e30f; sbz[i] = 1e30f; }
  __syncthreads();

  const int pid = t >> 4, q = t & 15;
  float ax[4], ay[4], az[4], mn[4];
  #pragma unroll
  for (int j = 0; j < 4; ++j) {
    const int n = n0 + pid * 4 + j;
    float4 P = *(const float4*)(pts + ((size_t)b * NPTS + n) * 4);
    ax[j] = P.x; ay[j] = P.y; az[j] = P.z + P.w; mn[j] = 1e30f;
  }
  #pragma unroll 4
  for (int i = 0; i < 32; ++i) {
    const int m4 = q * 4 + i * 64;
    float4 bx = *(const float4*)&sbx[m4];
    float4 by = *(const float4*)&sby[m4];
    float4 bz = *(const float4*)&sbz[m4];
    #pragma unroll
    for (int j = 0; j < 4; ++j) {
      float d0, dx, dy, dz;
      dx = ax[j] - bx.x; dy = ay[j] - by.x; dz = az[j] - bz.x; d0 = dx*dx + dy*dy + dz*dz; mn[j] = fminf(mn[j], d0);
      dx = ax[j] - bx.y; dy = ay[j] - by.y; dz = az[j] - bz.y; d0 = dx*dx + dy*dy + dz*dz; mn[j] = fminf(mn[j], d0);
      dx = ax[j] - bx.z; dy = ay[j] - by.z; dz = az[j] - bz.z; d0 = dx*dx + dy*dy + dz*dz; mn[j] = fminf(mn[j], d0);
      dx = ax[j] - bx.w; dy = ay[j] - by.w; dz = az[j] - bz.w; d0 = dx*dx + dy*dy + dz*dz; mn[j] = fminf(mn[j], d0);
    }
  }
  #pragma unroll
  for (int j = 0; j < 4; ++j) {
    mn[j] = fminf(mn[j], __shfl_xor(mn[j], 1));
    mn[j] = fminf(mn[j], __shfl_xor(mn[j], 2));
    mn[j] = fminf(mn[j], __shfl_xor(mn[j], 4));
    mn[j] = fminf(mn[j], __shfl_xor(mn[j], 8));
  }
  float v = (q == 0) ? (mn[0] + mn[1] + mn[2] + mn[3]) : 0.f;
  v += __shfl_xor(v, 16); v += __shfl_xor(v, 32);
  if ((t & 63) == 0) atomicAdd(lacc, v);
}

// =====================================================================
// Chamfer B: min over n for each (b,m). 512 blocks, 64 m/block.
// =====================================================================
__global__ __launch_bounds__(256) void chamB_kernel(const float* __restrict__ pts,
                                                    const float* __restrict__ pc,
                                                    float* __restrict__ lacc)
{
  __shared__ float sax[2048], say[2048], saz[2048];
  const int t = threadIdx.x;
  const int b = blockIdx.x >> 5;
  const int m0 = (blockIdx.x & 31) << 6;
  for (int i = t; i < NPTS; i += 256) {
    float4 pp = *(const float4*)(pts + ((size_t)b * NPTS + i) * 4);
    sax[i] = pp.x; say[i] = pp.y; saz[i] = pp.z + pp.w;
  }
  __syncthreads();

  const int pid = t >> 4, q = t & 15;
  float bx[4], by[4], bz[4], mn[4];
  bool vld[4];
  #pragma unroll
  for (int j = 0; j < 4; ++j) {
    const int m = m0 + pid * 4 + j;
    vld[j] = (m < MQ);
    const int mc = vld[j] ? m : (MQ - 1);
    bx[j] = pc[(size_t)b * (MQ * 3) + mc * 3 + 0];
    by[j] = pc[(size_t)b * (MQ * 3) + mc * 3 + 1];
    bz[j] = pc[(size_t)b * (MQ * 3) + mc * 3 + 2];
    mn[j] = 1e30f;
  }
  #pragma unroll 4
  for (int i = 0; i < 32; ++i) {
    const int n4 = q * 4 + i * 64;
    float4 axv = *(const float4*)&sax[n4];
    float4 ayv = *(const float4*)&say[n4];
    float4 azv = *(const float4*)&saz[n4];
    #pragma unroll
    for (int j = 0; j < 4; ++j) {
      float d0, dx, dy, dz;
      dx = axv.x - bx[j]; dy = ayv.x - by[j]; dz = azv.x - bz[j]; d0 = dx*dx + dy*dy + dz*dz; mn[j] = fminf(mn[j], d0);
      dx = axv.y - bx[j]; dy = ayv.y - by[j]; dz = azv.y - bz[j]; d0 = dx*dx + dy*dy + dz*dz; mn[j] = fminf(mn[j], d0);
      dx = axv.z - bx[j]; dy = ayv.z - by[j]; dz = azv.z - bz[j]; d0 = dx*dx + dy*dy + dz*dz; mn[j] = fminf(mn[j], d0);
      dx = axv.w - bx[j]; dy = ayv.w - by[j]; dz = azv.w - bz[j]; d0 = dx*dx + dy*dy + dz*dz; mn[j] = fminf(mn[j], d0);
    }
  }
  #pragma unroll
  for (int j = 0; j < 4; ++j) {
    mn[j] = fminf(mn[j], __shfl_xor(mn[j], 1));
    mn[j] = fminf(mn[j], __shfl_xor(mn[j], 2));
    mn[j] = fminf(mn[j], __shfl_xor(mn[j], 4));
    mn[j] = fminf(mn[j], __shfl_xor(mn[j], 8));
  }
  float v = 0.f;
  if (q == 0) {
    #pragma unroll
    for (int j = 0; j < 4; ++j) if (vld[j]) v += mn[j];
  }
  v += __shfl_xor(v, 16); v += __shfl_xor(v, 32);
  if ((t & 63) == 0) atomicAdd(lacc + 1, v);
}

__global__ void fin_kernel(const float* __restrict__ lacc, float* __restrict__ loss) {
  if (threadIdx.x == 0 && blockIdx.x == 0)
    loss[0] = lacc[0] * (1.0f / (NBATCH * NPTS)) + lacc[1] * (1.0f / (NBATCH * MQ));
}

// =====================================================================
extern "C" void kernel_launch(void* const* d_in, const int* in_sizes, int n_in,
                              void* d_out, int out_size, void* d_ws, size_t ws_size,
                              hipStream_t stream) {
  const float* pts  = (const float*)d_in[0];
  const float* ew1  = (const float*)d_in[1];
  const float* eb1  = (const float*)d_in[2];
  const float* ew2  = (const float*)d_in[3];
  const float* eb2  = (const float*)d_in[4];
  const float* ew3  = (const float*)d_in[5];
  const float* eb3  = (const float*)d_in[6];
  const float* f1w1 = (const float*)d_in[7];
  const float* f1b1 = (const float*)d_in[8];
  const float* f1w2 = (const float*)d_in[9];
  const float* f1b2 = (const float*)d_in[10];
  const float* f1w3 = (const float*)d_in[11];
  const float* f1b3 = (const float*)d_in[12];
  const float* f2w1 = (const float*)d_in[13];
  const float* f2b1 = (const float*)d_in[14];
  const float* f2w2 = (const float*)d_in[15];
  const float* f2b2 = (const float*)d_in[16];
  const float* f2w3 = (const float*)d_in[17];
  const float* f2b3 = (const float*)d_in[18];
  const float* grid2= (const float*)d_in[19];

  float* out = (float*)d_out;
  unsigned* keys       = (unsigned*)d_ws;                              // 32768 B
  float* lacc          = (float*)((char*)d_ws + 32768);                // -> 33024
  float* h1b           = (float*)((char*)d_ws + 33024);                // 65536 B -> 98560
  unsigned short* w2T  = (unsigned short*)((char*)d_ws + 98560);       // 1 MB -> 1147136
  unsigned short* ew2T = (unsigned short*)((char*)d_ws + 1147136);     // 16 KB
  unsigned short* ew3T = (unsigned short*)((char*)d_ws + 1163520);     // 128 KB

  hipMemsetAsync(d_ws, 0, 98560, stream);   // keys + lacc + h1b

  tconv_kernel<<<584, 256, 0, stream>>>(f1w2, f2w2, ew2, ew3, w2T, ew2T, ew3T);
  enc2_kernel<<<512, 512, 0, stream>>>(pts, ew1, eb1, ew2T, eb2, ew3T, eb3, keys);
  decode_kernel<<<32, 256, 0, stream>>>(keys, out);                    // theta
  h1base_kernel<<<128, 256, 0, stream>>>(out, f1w1, f1b1, f2w1, f2b1, h1b);
  fold2_kernel<<<675, 512, 0, stream>>>(grid2, h1b, w2T,
                                        f1w1, f1b2, f1w3, f1b3,
                                        f2w1, f2b2, f2w3, f2b3,
                                        out + 8192);                   // pc_out
  chamA_kernel<<<512, 256, 0, stream>>>(pts, out + 8192, lacc);
  chamB_kernel<<<512, 256, 0, stream>>>(pts, out + 8192, lacc);
  fin_kernel<<<1, 64, 0, stream>>>(lacc, out + 8192 + 97200);          // loss
}